// Round 1
// baseline (266.192 us; speedup 1.0000x reference)
//
#include <hip/hip_runtime.h>

// LSTM B=4096, S=512, INPUT=1, HIDDEN=20 + linear head.
// Mapping: 20 lanes per chain (lane = hidden unit), 3 chains per 64-thread
// block (lanes 60..63 ride along as a dummy 4th group, never store).
// Per step: gates accumulated with pre-scaled weights so sigmoid/tanh are
// rcp(1+exp2(acc)) with no extra scale mul. h broadcast via per-group LDS
// ring buffer (16 rows); head (h . W_lin) deferred: after each 16-step chunk,
// lanes 0..15 reduce one stored row each -> coalesced 16-float store.

#define BATCH 4096
#define SLEN  512
#define H     20
#define CHUNK 16
#define LOG2E 1.44269504088896340736f

__device__ __forceinline__ float fexp2(float x) { return __builtin_amdgcn_exp2f(x); }
__device__ __forceinline__ float frcp(float x)  { return __builtin_amdgcn_rcpf(x); }

__global__ __launch_bounds__(64, 1) void lstm_fused(
    const float* __restrict__ x,      // [B, S, 1]
    const float* __restrict__ W_ih,   // [80, 1]
    const float* __restrict__ W_hh,   // [80, 20]
    const float* __restrict__ b_ih,   // [80]
    const float* __restrict__ b_hh,   // [80]
    const float* __restrict__ W_lin,  // [1, 20]
    const float* __restrict__ b_lin,  // [1]
    float* __restrict__ out)          // [B, S, 1]
{
    __shared__ __align__(16) float hbuf[4][CHUNK][H];  // [group][step%16][unit]
    __shared__ float xbuf[4][CHUNK];

    const int lane = threadIdx.x;           // 0..63
    int grp = lane / H;                     // 0..3 (3 = dummy group)
    const int j = lane - grp * H;           // 0..19 (0..3 for dummy)
    const long b = (long)blockIdx.x * 3 + grp;
    const bool valid = (grp < 3) && (b < BATCH);
    const long bc = valid ? b : 0;          // clamp addresses for dummy lanes

    const float s1 = -LOG2E;         // sigmoid pre-scale
    const float s2 = -2.0f * LOG2E;  // tanh pre-scale

    // ---- load per-unit weights into registers, pre-scaled ----
    float wI[H], wF[H], wG[H], wO[H], wL[H];
#pragma unroll
    for (int k4 = 0; k4 < 5; ++k4) {
        float4 vi = *(const float4*)(W_hh + (0 * H + j) * H + k4 * 4);
        float4 vf = *(const float4*)(W_hh + (1 * H + j) * H + k4 * 4);
        float4 vg = *(const float4*)(W_hh + (2 * H + j) * H + k4 * 4);
        float4 vo = *(const float4*)(W_hh + (3 * H + j) * H + k4 * 4);
        float4 vl = *(const float4*)(W_lin + k4 * 4);
        wI[k4 * 4 + 0] = s1 * vi.x; wI[k4 * 4 + 1] = s1 * vi.y;
        wI[k4 * 4 + 2] = s1 * vi.z; wI[k4 * 4 + 3] = s1 * vi.w;
        wF[k4 * 4 + 0] = s1 * vf.x; wF[k4 * 4 + 1] = s1 * vf.y;
        wF[k4 * 4 + 2] = s1 * vf.z; wF[k4 * 4 + 3] = s1 * vf.w;
        wG[k4 * 4 + 0] = s2 * vg.x; wG[k4 * 4 + 1] = s2 * vg.y;
        wG[k4 * 4 + 2] = s2 * vg.z; wG[k4 * 4 + 3] = s2 * vg.w;
        wO[k4 * 4 + 0] = s1 * vo.x; wO[k4 * 4 + 1] = s1 * vo.y;
        wO[k4 * 4 + 2] = s1 * vo.z; wO[k4 * 4 + 3] = s1 * vo.w;
        wL[k4 * 4 + 0] = vl.x; wL[k4 * 4 + 1] = vl.y;
        wL[k4 * 4 + 2] = vl.z; wL[k4 * 4 + 3] = vl.w;
    }
    const float bI  = s1 * (b_ih[0 * H + j] + b_hh[0 * H + j]);
    const float bF  = s1 * (b_ih[1 * H + j] + b_hh[1 * H + j]);
    const float bG  = s2 * (b_ih[2 * H + j] + b_hh[2 * H + j]);
    const float bO  = s1 * (b_ih[3 * H + j] + b_hh[3 * H + j]);
    const float xwI = s1 * W_ih[0 * H + j];
    const float xwF = s1 * W_ih[1 * H + j];
    const float xwG = s2 * W_ih[2 * H + j];
    const float xwO = s1 * W_ih[3 * H + j];
    const float blin = b_lin[0];

    const float* xb = x + bc * SLEN;
    float* ob = out + bc * SLEN;

    // h(-1) = 0 lives in ring row CHUNK-1
    hbuf[grp][CHUNK - 1][j] = 0.0f;
    float c = 0.0f;

#pragma unroll 1
    for (int T = 0; T < SLEN; T += CHUNK) {
        if (j < CHUNK) xbuf[grp][j] = xb[T + j];   // coalesced x chunk -> LDS

#pragma unroll
        for (int i = 0; i < CHUNK; ++i) {
            const int rp = (i + CHUNK - 1) & (CHUNK - 1);  // row of h(t-1)
            const float xt = xbuf[grp][i];                 // LDS broadcast
            float aI = fmaf(xt, xwI, bI);
            float aF = fmaf(xt, xwF, bF);
            float aG = fmaf(xt, xwG, bG);
            float aO = fmaf(xt, xwO, bO);
#pragma unroll
            for (int k4 = 0; k4 < 5; ++k4) {
                const float4 h4 = *(const float4*)&hbuf[grp][rp][k4 * 4];  // broadcast
                aI = fmaf(h4.x, wI[k4 * 4 + 0], aI);
                aF = fmaf(h4.x, wF[k4 * 4 + 0], aF);
                aG = fmaf(h4.x, wG[k4 * 4 + 0], aG);
                aO = fmaf(h4.x, wO[k4 * 4 + 0], aO);
                aI = fmaf(h4.y, wI[k4 * 4 + 1], aI);
                aF = fmaf(h4.y, wF[k4 * 4 + 1], aF);
                aG = fmaf(h4.y, wG[k4 * 4 + 1], aG);
                aO = fmaf(h4.y, wO[k4 * 4 + 1], aO);
                aI = fmaf(h4.z, wI[k4 * 4 + 2], aI);
                aF = fmaf(h4.z, wF[k4 * 4 + 2], aF);
                aG = fmaf(h4.z, wG[k4 * 4 + 2], aG);
                aO = fmaf(h4.z, wO[k4 * 4 + 2], aO);
                aI = fmaf(h4.w, wI[k4 * 4 + 3], aI);
                aF = fmaf(h4.w, wF[k4 * 4 + 3], aF);
                aG = fmaf(h4.w, wG[k4 * 4 + 3], aG);
                aO = fmaf(h4.w, wO[k4 * 4 + 3], aO);
            }
            // activations: weights pre-scaled, so sigmoid = rcp(1+exp2(a))
            const float gi = frcp(1.0f + fexp2(aI));
            const float gf = frcp(1.0f + fexp2(aF));
            const float gg = fmaf(2.0f, frcp(1.0f + fexp2(aG)), -1.0f); // tanh
            const float go = frcp(1.0f + fexp2(aO));
            c = fmaf(gf, c, gi * gg);
            const float tc = fmaf(2.0f, frcp(1.0f + fexp2(s2 * c)), -1.0f);
            const float h = go * tc;
            hbuf[grp][i][j] = h;   // publish h(t) for next step + head
        }

        // ---- deferred head: lane t' reduces step T+t' ----
        if (j < CHUNK) {
            float y = blin;
#pragma unroll
            for (int k4 = 0; k4 < 5; ++k4) {
                const float4 h4 = *(const float4*)&hbuf[grp][j][k4 * 4];
                y = fmaf(h4.x, wL[k4 * 4 + 0], y);
                y = fmaf(h4.y, wL[k4 * 4 + 1], y);
                y = fmaf(h4.z, wL[k4 * 4 + 2], y);
                y = fmaf(h4.w, wL[k4 * 4 + 3], y);
            }
            if (valid) ob[T + j] = y;   // coalesced 16-float burst per chain
        }
    }
}

extern "C" void kernel_launch(void* const* d_in, const int* in_sizes, int n_in,
                              void* d_out, int out_size, void* d_ws, size_t ws_size,
                              hipStream_t stream) {
    const float* x     = (const float*)d_in[0];
    const float* W_ih  = (const float*)d_in[1];
    const float* W_hh  = (const float*)d_in[2];
    const float* b_ih  = (const float*)d_in[3];
    const float* b_hh  = (const float*)d_in[4];
    const float* W_lin = (const float*)d_in[5];
    const float* b_lin = (const float*)d_in[6];
    float* out = (float*)d_out;

    const int nblocks = (BATCH + 2) / 3;  // 3 chains per 64-thread block
    lstm_fused<<<nblocks, 64, 0, stream>>>(x, W_ih, W_hh, b_ih, b_hh,
                                           W_lin, b_lin, out);
}